// Round 2
// baseline (161.732 us; speedup 1.0000x reference)
//
#include <hip/hip_runtime.h>

// LBP block — single fused kernel, 2 output rows per wave.
// block = 256 threads (4 waves) = (n, 8-row tile, group of 16 channels).
// Each wave owns rows hrow0, hrow0+1 and is self-sufficient: its 4 x-rows x 3
// input channels live in 12 float4 registers; the 16-channel loop is pure
// register VALU + 8 shuffles (4 y-rows serve 2 output rows -> 2x redundancy
// instead of 3x). y recompute across waves is bit-identical (same contract-off
// expression, same inputs). One __syncthreads total (exp(w) table).
// og==0 blocks also emit the x-copy channels from already-loaded registers.
//
// R1/R2 changes (occupancy theory): the kernel was ~65 us vs a ~26-30 us
// latency-hidden floor -> latency-bound, most likely 2 waves/SIMD from
// >128 VGPRs (unroll-4 kept multiple channels' Y + shuffle results live).
//  - __launch_bounds__(256, 4): cap VGPRs at 128 -> 4 waves/SIMD.
//  - unroll 2 instead of 4: halve duplicated live state under the cap.
//  - exp(w) values are wave-uniform: readfirstlane them into SGPRs
//    (frees VGPRs; v_cndmask can take the SGPR operand directly).
//  - nontemporal stores for the write-only output, via a NATIVE
//    ext_vector_type(4) alias (the builtin rejects HIP_vector_type).
//
// Numerics (do not change): y = (x0*cw0 + x1*cw1) + x2*cw2 sequentially with
// FMA contraction OFF to match the numpy reference; (c - s > 0) == (c > s)
// exactly for finite floats.

typedef float vfloat4 __attribute__((ext_vector_type(4)));

__device__ __forceinline__ void store_nt4(float* p, float a, float b, float c, float d) {
    vfloat4 v; v.x = a; v.y = b; v.z = c; v.w = d;
    __builtin_nontemporal_store(v, (vfloat4*)p);
}

__device__ __forceinline__ void store_nt4f(float* p, float4 v) {
    store_nt4(p, v.x, v.y, v.z, v.w);
}

__global__ __launch_bounds__(256, 4) void lbp_all(
    const float* __restrict__ x,
    const float* __restrict__ conv_w,
    const float* __restrict__ w,
    float* __restrict__ out)
{
#pragma clang fp contract(off)
    const int n     = blockIdx.z;
    const int og    = blockIdx.y;            // channels og*16 .. og*16+15
    const int tid   = threadIdx.x;
    const int lane  = tid & 63;
    const int wv    = tid >> 6;              // wave 0..3
    const int col   = lane * 4;
    const int hrow0 = blockIdx.x * 8 + wv * 2;   // wave's first output row

    __shared__ float ews[128];               // exp(w) for this block's 16 ch
    if (tid < 128) ews[tid] = expf(w[og * 128 + tid]);

    const float* xn = x + (size_t)n * 3 * 65536;

    // x rows hrow0-1 .. hrow0+2 (clamped), 3 input channels, in registers.
    float4 xr[4][3];
    #pragma unroll
    for (int r = 0; r < 4; ++r) {
        int row = hrow0 - 1 + r;
        row = row < 0 ? 0 : (row > 255 ? 255 : row);
        #pragma unroll
        for (int ch = 0; ch < 3; ++ch)
            xr[r][ch] = *(const float4*)(xn + (ch * 256 + row) * 256 + col);
    }

    if (og == 0) {  // copy channels 0..2; xr[1]=row hrow0, xr[2]=row hrow0+1
        #pragma unroll
        for (int ch = 0; ch < 3; ++ch) {
            float* cp = out + ((((size_t)n * 67 + ch) * 256 + hrow0) * 256 + col);
            store_nt4f(cp,       xr[1][ch]);
            store_nt4f(cp + 256, xr[2][ch]);
        }
    }

    __syncthreads();

    float* obase = out + ((((size_t)n * 67 + 3 + og * 16) * 256 + hrow0) * 256 + col);

    #pragma unroll 2
    for (int oi = 0; oi < 16; ++oi) {
        // e-table reads issued first (two b128 ds_reads) so their latency
        // hides under the conv VALU below; values are wave-uniform ->
        // readfirstlane moves them to SGPRs (saves 8 VGPRs per live iter).
        const float4 eA = *(const float4*)&ews[oi * 8 + 0];
        const float4 eB = *(const float4*)&ews[oi * 8 + 4];
        const float e0 = __uint_as_float(__builtin_amdgcn_readfirstlane(__float_as_uint(eA.x)));
        const float e1 = __uint_as_float(__builtin_amdgcn_readfirstlane(__float_as_uint(eA.y)));
        const float e2 = __uint_as_float(__builtin_amdgcn_readfirstlane(__float_as_uint(eA.z)));
        const float e3 = __uint_as_float(__builtin_amdgcn_readfirstlane(__float_as_uint(eA.w)));
        const float e4 = __uint_as_float(__builtin_amdgcn_readfirstlane(__float_as_uint(eB.x)));
        const float e5 = __uint_as_float(__builtin_amdgcn_readfirstlane(__float_as_uint(eB.y)));
        const float e6 = __uint_as_float(__builtin_amdgcn_readfirstlane(__float_as_uint(eB.z)));
        const float e7 = __uint_as_float(__builtin_amdgcn_readfirstlane(__float_as_uint(eB.w)));

        const int o = og * 16 + oi;
        const float cw0 = conv_w[o * 3 + 0];
        const float cw1 = conv_w[o * 3 + 1];
        const float cw2 = conv_w[o * 3 + 2];

        // Y[r][k] = y at row hrow0-1+r, col (col-1+k), k=0..5; halo via shfl.
        float Y[4][6];
        #pragma unroll
        for (int r = 0; r < 4; ++r) {
            float4 yv;
            yv.x = xr[r][0].x * cw0 + xr[r][1].x * cw1 + xr[r][2].x * cw2;
            yv.y = xr[r][0].y * cw0 + xr[r][1].y * cw1 + xr[r][2].y * cw2;
            yv.z = xr[r][0].z * cw0 + xr[r][1].z * cw1 + xr[r][2].z * cw2;
            yv.w = xr[r][0].w * cw0 + xr[r][1].w * cw1 + xr[r][2].w * cw2;
            Y[r][1] = yv.x; Y[r][2] = yv.y; Y[r][3] = yv.z; Y[r][4] = yv.w;
            Y[r][0] = __shfl_up(yv.w, 1);   // lane 0 garbage -> col 0 zeroed
            Y[r][5] = __shfl_down(yv.x, 1); // lane 63 garbage -> col 255 zeroed
        }

        #pragma unroll
        for (int k = 0; k < 2; ++k) {        // the wave's two output rows
            const int hrow = hrow0 + k;
            float res[4];
            if (hrow == 0 || hrow == 255) {  // wave-uniform branch
                res[0] = res[1] = res[2] = res[3] = 0.f;
            } else {
                const float* up  = Y[k];
                const float* mid = Y[k + 1];
                const float* dn  = Y[k + 2];
                #pragma unroll
                for (int j = 0; j < 4; ++j) {
                    const float c = mid[j + 1];
                    float acc;
                    acc  = (c > up [j    ]) ? e0 : 0.f;   // (-1,-1)
                    acc += (c > up [j + 1]) ? e1 : 0.f;   // (-1, 0)
                    acc += (c > up [j + 2]) ? e2 : 0.f;   // (-1,+1)
                    acc += (c > mid[j    ]) ? e3 : 0.f;   // ( 0,-1)
                    acc += (c > dn [j    ]) ? e4 : 0.f;   // (+1,-1)
                    acc += (c > dn [j + 1]) ? e5 : 0.f;   // (+1, 0)
                    acc += (c > dn [j + 2]) ? e6 : 0.f;   // (+1,+1)
                    acc += (c > mid[j + 2]) ? e7 : 0.f;   // ( 0,+1)
                    res[j] = acc;
                }
                if (lane == 0)  res[0] = 0.f;   // col 0
                if (lane == 63) res[3] = 0.f;   // col 255
            }
            store_nt4(obase + (size_t)oi * 65536 + (size_t)k * 256,
                      res[0], res[1], res[2], res[3]);
        }
    }
}

extern "C" void kernel_launch(void* const* d_in, const int* in_sizes, int n_in,
                              void* d_out, int out_size, void* d_ws, size_t ws_size,
                              hipStream_t stream) {
    const float* x      = (const float*)d_in[0];
    const float* conv_w = (const float*)d_in[1];
    const float* w      = (const float*)d_in[2];
    float* out          = (float*)d_out;

    dim3 grid(32, 4, 8);   // (8-row tiles, channel groups of 16, batch)
    dim3 block(256);
    hipLaunchKernelGGL(lbp_all, grid, block, 0, stream, x, conv_w, w, out);
}

// Round 3
// 152.632 us; speedup vs baseline: 1.0596x; 1.0596x over previous
//
#include <hip/hip_runtime.h>

// LBP block — single fused kernel, 2 output rows per wave.
// block = 256 threads (4 waves) = (n, 8-row tile, group of 16 channels).
// Each wave owns rows hrow0, hrow0+1 and is self-sufficient: its 4 x-rows x 3
// input channels live in 12 float4 registers; the 16-channel loop is pure
// register VALU + 8 halo shifts (4 y-rows serve 2 output rows -> 2x redundancy
// instead of 3x). y recompute across waves is bit-identical (same contract-off
// expression, same inputs). One __syncthreads total (exp(w) table).
// og==0 blocks also emit the x-copy channels from already-loaded registers.
//
// R3 change (isolated, vs the 152.5us baseline): halo exchange via DPP
// wavefront shifts instead of __shfl_up/__shfl_down. __shfl lowers to
// ds_permute (LDS path, lgkmcnt latency); the kernel issued 128 of them per
// wave, each immediately consumed -> latency-bound at ~65us vs a ~25-30us
// roofline. v_mov_b32_dpp wave_shr:1 / wave_shl:1 are single VALU ops:
//   wave_shr:1 -> lane i gets lane i-1  == __shfl_up(x, 1)
//   wave_shl:1 -> lane i gets lane i+1  == __shfl_down(x, 1)
// Out-of-range lanes keep 'old' (=0); the only consumers of those slots
// (res[0] at lane 0, res[3] at lane 63) are zeroed afterward, so output is
// bit-identical. (R2's bundle of cap+unroll2+readfirstlane+nt regressed and
// is fully reverted.)
//
// Numerics (do not change): y = (x0*cw0 + x1*cw1) + x2*cw2 sequentially with
// FMA contraction OFF to match the numpy reference; (c - s > 0) == (c > s)
// exactly for finite floats.

__device__ __forceinline__ float wave_shr1(float v) {   // lane i <- lane i-1
    return __int_as_float(
        __builtin_amdgcn_update_dpp(0, __float_as_int(v), 0x138, 0xf, 0xf, false));
}
__device__ __forceinline__ float wave_shl1(float v) {   // lane i <- lane i+1
    return __int_as_float(
        __builtin_amdgcn_update_dpp(0, __float_as_int(v), 0x130, 0xf, 0xf, false));
}

__global__ __launch_bounds__(256) void lbp_all(
    const float* __restrict__ x,
    const float* __restrict__ conv_w,
    const float* __restrict__ w,
    float* __restrict__ out)
{
#pragma clang fp contract(off)
    const int n     = blockIdx.z;
    const int og    = blockIdx.y;            // channels og*16 .. og*16+15
    const int tid   = threadIdx.x;
    const int lane  = tid & 63;
    const int wv    = tid >> 6;              // wave 0..3
    const int col   = lane * 4;
    const int hrow0 = blockIdx.x * 8 + wv * 2;   // wave's first output row

    __shared__ float ews[128];               // exp(w) for this block's 16 ch
    if (tid < 128) ews[tid] = expf(w[og * 128 + tid]);

    const float* xn = x + (size_t)n * 3 * 65536;

    // x rows hrow0-1 .. hrow0+2 (clamped), 3 input channels, in registers.
    float4 xr[4][3];
    #pragma unroll
    for (int r = 0; r < 4; ++r) {
        int row = hrow0 - 1 + r;
        row = row < 0 ? 0 : (row > 255 ? 255 : row);
        #pragma unroll
        for (int ch = 0; ch < 3; ++ch)
            xr[r][ch] = *(const float4*)(xn + (ch * 256 + row) * 256 + col);
    }

    if (og == 0) {  // copy channels 0..2; xr[1]=row hrow0, xr[2]=row hrow0+1
        #pragma unroll
        for (int ch = 0; ch < 3; ++ch) {
            float* cp = out + ((((size_t)n * 67 + ch) * 256 + hrow0) * 256 + col);
            *(float4*)cp         = xr[1][ch];
            *(float4*)(cp + 256) = xr[2][ch];
        }
    }

    __syncthreads();

    float* obase = out + ((((size_t)n * 67 + 3 + og * 16) * 256 + hrow0) * 256 + col);

    #pragma unroll 4
    for (int oi = 0; oi < 16; ++oi) {
        const int o = og * 16 + oi;
        const float cw0 = conv_w[o * 3 + 0];
        const float cw1 = conv_w[o * 3 + 1];
        const float cw2 = conv_w[o * 3 + 2];

        // Y[r][k] = y at row hrow0-1+r, col (col-1+k), k=0..5; halo via DPP.
        float Y[4][6];
        #pragma unroll
        for (int r = 0; r < 4; ++r) {
            float4 yv;
            yv.x = xr[r][0].x * cw0 + xr[r][1].x * cw1 + xr[r][2].x * cw2;
            yv.y = xr[r][0].y * cw0 + xr[r][1].y * cw1 + xr[r][2].y * cw2;
            yv.z = xr[r][0].z * cw0 + xr[r][1].z * cw1 + xr[r][2].z * cw2;
            yv.w = xr[r][0].w * cw0 + xr[r][1].w * cw1 + xr[r][2].w * cw2;
            Y[r][1] = yv.x; Y[r][2] = yv.y; Y[r][3] = yv.z; Y[r][4] = yv.w;
            Y[r][0] = wave_shr1(yv.w);   // lane 0 gets 0 -> col 0 zeroed below
            Y[r][5] = wave_shl1(yv.x);   // lane 63 gets 0 -> col 255 zeroed below
        }

        const float e0 = ews[oi * 8 + 0], e1 = ews[oi * 8 + 1];
        const float e2 = ews[oi * 8 + 2], e3 = ews[oi * 8 + 3];
        const float e4 = ews[oi * 8 + 4], e5 = ews[oi * 8 + 5];
        const float e6 = ews[oi * 8 + 6], e7 = ews[oi * 8 + 7];

        #pragma unroll
        for (int k = 0; k < 2; ++k) {        // the wave's two output rows
            const int hrow = hrow0 + k;
            float res[4];
            if (hrow == 0 || hrow == 255) {  // wave-uniform branch
                res[0] = res[1] = res[2] = res[3] = 0.f;
            } else {
                const float* up  = Y[k];
                const float* mid = Y[k + 1];
                const float* dn  = Y[k + 2];
                #pragma unroll
                for (int j = 0; j < 4; ++j) {
                    const float c = mid[j + 1];
                    float acc;
                    acc  = (c > up [j    ]) ? e0 : 0.f;   // (-1,-1)
                    acc += (c > up [j + 1]) ? e1 : 0.f;   // (-1, 0)
                    acc += (c > up [j + 2]) ? e2 : 0.f;   // (-1,+1)
                    acc += (c > mid[j    ]) ? e3 : 0.f;   // ( 0,-1)
                    acc += (c > dn [j    ]) ? e4 : 0.f;   // (+1,-1)
                    acc += (c > dn [j + 1]) ? e5 : 0.f;   // (+1, 0)
                    acc += (c > dn [j + 2]) ? e6 : 0.f;   // (+1,+1)
                    acc += (c > mid[j + 2]) ? e7 : 0.f;   // ( 0,+1)
                    res[j] = acc;
                }
                if (lane == 0)  res[0] = 0.f;   // col 0
                if (lane == 63) res[3] = 0.f;   // col 255
            }
            *(float4*)(obase + (size_t)oi * 65536 + (size_t)k * 256) =
                make_float4(res[0], res[1], res[2], res[3]);
        }
    }
}

extern "C" void kernel_launch(void* const* d_in, const int* in_sizes, int n_in,
                              void* d_out, int out_size, void* d_ws, size_t ws_size,
                              hipStream_t stream) {
    const float* x      = (const float*)d_in[0];
    const float* conv_w = (const float*)d_in[1];
    const float* w      = (const float*)d_in[2];
    float* out          = (float*)d_out;

    dim3 grid(32, 4, 8);   // (8-row tiles, channel groups of 16, batch)
    dim3 block(256);
    hipLaunchKernelGGL(lbp_all, grid, block, 0, stream, x, conv_w, w, out);
}